// Round 1
// baseline (755.839 us; speedup 1.0000x reference)
//
#include <hip/hip_runtime.h>
#include <cmath>

#define NL 512
#define SS 10
#define DD 128
#define HWC (128 * 128)
#define LDK 36

// ---------------- transpose (D, HW) -> (HW, D), both images ----------------
__global__ __launch_bounds__(256) void transpose_kernel(
    const float* __restrict__ in1, const float* __restrict__ in2,
    float* __restrict__ out1, float* __restrict__ out2)
{
    const float* in = blockIdx.z ? in2 : in1;
    float* out = blockIdx.z ? out2 : out1;
    __shared__ float tile[32][33];
    int hw0 = blockIdx.x * 32;
    int d0 = blockIdx.y * 32;
    int tx = threadIdx.x, ty = threadIdx.y;  // 32 x 8
#pragma unroll
    for (int j = 0; j < 32; j += 8)
        tile[ty + j][tx] = in[(size_t)(d0 + ty + j) * HWC + hw0 + tx];
    __syncthreads();
#pragma unroll
    for (int j = 0; j < 32; j += 8)
        out[(size_t)(hw0 + ty + j) * DD + d0 + tx] = tile[tx][ty + j];
}

// ---------------- sample points + bilinear + normalize ----------------
__device__ __forceinline__ float fetchd(const float* __restrict__ dt, int y, int x, int d)
{
    bool inb = (x >= 0) && (x < 128) && (y >= 0) && (y < 128);
    int yc = y < 0 ? 0 : (y > 127 ? 127 : y);
    int xc = x < 0 ? 0 : (x > 127 ? 127 : x);
    float v = dt[((size_t)(yc * 128 + xc)) * DD + d];
    return inb ? v : 0.0f;
}

__global__ __launch_bounds__(128) void sample_kernel(
    const float* __restrict__ seg1, const float* __restrict__ seg2,
    const float* __restrict__ dt1, const float* __restrict__ dt2,
    float* __restrict__ dd1, float* __restrict__ dd2,
    int* __restrict__ v1, int* __restrict__ v2)
{
#pragma clang fp contract(off)
    int L = blockIdx.x;
    int img = blockIdx.y;
    const float* seg = img ? seg2 : seg1;
    const float* dt = img ? dt2 : dt1;
    float* dd = img ? dd2 : dd1;
    int* vv = img ? v2 : v1;

    float p0y = seg[L * 4 + 0], p0x = seg[L * 4 + 1];
    float p1y = seg[L * 4 + 2], p1x = seg[L * 4 + 3];
    float dy = p0y - p1y, dx = p0x - p1x;
    float len = sqrtf(dy * dy + dx * dx);
    float nf = floorf(len / 8.0f);
    nf = fminf(fmaxf(nf, 2.0f), 10.0f);
    int ni = (int)nf;
    float ivy = (p1y - p0y) / (nf - 1.0f);
    float ivx = (p1x - p0x) / (nf - 1.0f);

    int d = threadIdx.x;
    __shared__ float red[128];

    for (int t = 0; t < SS; ++t) {
        int pt = L * SS + t;
        bool val = t < ni;  // block-uniform
        float outv = 0.0f;
        if (val) {
            float py = p0y + (float)t * ivy;
            float px = p0x + (float)t * ivx;
            float gx = 2.0f * px / 511.0f - 1.0f;
            float gy = 2.0f * py / 511.0f - 1.0f;
            float ix = ((gx + 1.0f) * 128.0f - 1.0f) / 2.0f;
            float iy = ((gy + 1.0f) * 128.0f - 1.0f) / 2.0f;
            float x0f = floorf(ix), y0f = floorf(iy);
            float wx = ix - x0f, wy = iy - y0f;
            int x0 = (int)x0f, y0 = (int)y0f;
            float g00 = fetchd(dt, y0, x0, d);
            float g01 = fetchd(dt, y0, x0 + 1, d);
            float g10 = fetchd(dt, y0 + 1, x0, d);
            float g11 = fetchd(dt, y0 + 1, x0 + 1, d);
            float omwx = 1.0f - wx, omwy = 1.0f - wy;
            float v = g00 * omwy * omwx + g01 * omwy * wx + g10 * wy * omwx + g11 * wy * wx;
            red[d] = v * v;
            __syncthreads();
            for (int s = 64; s > 0; s >>= 1) {
                if (d < s) red[d] += red[d + s];
                __syncthreads();
            }
            float nrm = sqrtf(red[0]);
            outv = v / fmaxf(nrm, 1e-12f);
        }
        dd[(size_t)pt * DD + d] = outv;
        if (d == 0) vv[pt] = val ? 1 : 0;
        __syncthreads();
    }
}

// ---------------- GEMM (16x16 lines per block) + fused line-score ----------------
__global__ __launch_bounds__(256, 2) void gemm_ls_kernel(
    const float* __restrict__ d1, const float* __restrict__ d2,
    const int* __restrict__ v1, const int* __restrict__ v2,
    float* __restrict__ ls)
{
    __shared__ float As[160 * LDK];
    __shared__ float Bs[160 * LDK];
    int tid = threadIdx.x;
    int tx = tid & 15, ty = tid >> 4;
    int bi = blockIdx.y, bj = blockIdx.x;

    float acc[10][10];
#pragma unroll
    for (int i = 0; i < 10; ++i)
#pragma unroll
        for (int j = 0; j < 10; ++j) acc[i][j] = 0.0f;

    for (int kt = 0; kt < 4; ++kt) {
        __syncthreads();
#pragma unroll
        for (int it = 0; it < 5; ++it) {
            int f = tid + it * 256;       // 0..1279
            int row = f >> 3;             // 0..159
            int c4 = (f & 7) << 2;        // 0..28
            float4 a = *(const float4*)&d1[((size_t)(bi * 160 + row)) * DD + kt * 32 + c4];
            *(float4*)&As[row * LDK + c4] = a;
            int pl = row / 10, pts = row - pl * 10;
            int prow = pts * 16 + pl;     // t-major layout for B
            float4 b = *(const float4*)&d2[((size_t)(bj * 160 + row)) * DD + kt * 32 + c4];
            *(float4*)&Bs[prow * LDK + c4] = b;
        }
        __syncthreads();
#pragma unroll
        for (int k4 = 0; k4 < 8; ++k4) {
            float4 av[10];
#pragma unroll
            for (int i = 0; i < 10; ++i)
                av[i] = *(const float4*)&As[(ty * 10 + i) * LDK + k4 * 4];
#pragma unroll
            for (int j = 0; j < 10; ++j) {
                float4 b = *(const float4*)&Bs[(j * 16 + tx) * LDK + k4 * 4];
#pragma unroll
                for (int i = 0; i < 10; ++i) {
                    acc[i][j] = fmaf(av[i].x, b.x, acc[i][j]);
                    acc[i][j] = fmaf(av[i].y, b.y, acc[i][j]);
                    acc[i][j] = fmaf(av[i].z, b.z, acc[i][j]);
                    acc[i][j] = fmaf(av[i].w, b.w, acc[i][j]);
                }
            }
        }
    }

    // per-thread pair reduction: this thread owns the full 10x10 block of (iL, jL)
    int iL = bi * 16 + ty;
    int jL = bj * 16 + tx;
    int va[10], vb[10];
#pragma unroll
    for (int s = 0; s < 10; ++s) va[s] = v1[iL * 10 + s];
#pragma unroll
    for (int t = 0; t < 10; ++t) vb[t] = v2[jL * 10 + t];

    float sum1 = 0.0f; int c1 = 0;
#pragma unroll
    for (int s = 0; s < 10; ++s) {
        float mx = -3.0e38f;
#pragma unroll
        for (int t = 0; t < 10; ++t) {
            float v = (va[s] && vb[t]) ? acc[s][t] : -1.0f;
            mx = fmaxf(mx, v);
        }
        if (mx != -1.0f) { sum1 += mx; c1++; }
    }
    float sum2 = 0.0f; int c2 = 0;
#pragma unroll
    for (int t = 0; t < 10; ++t) {
        float mx = -3.0e38f;
#pragma unroll
        for (int s = 0; s < 10; ++s) {
            float v = (va[s] && vb[t]) ? acc[s][t] : -1.0f;
            mx = fmaxf(mx, v);
        }
        if (mx != -1.0f) { sum2 += mx; c2++; }
    }
    ls[(size_t)iL * NL + jL] = (sum1 / (float)c1 + sum2 / (float)c2) * 0.5f;
}

// ---------------- top-10 per row (dir 0) / per col (dir 1), stable-argsort order ----
__global__ __launch_bounds__(512) void topk_kernel(
    const float* __restrict__ ls, int* __restrict__ topk)
{
    int dir = blockIdx.x;
    int i = threadIdx.x;
    float bv[10];
    int bx[10];
#pragma unroll
    for (int p = 0; p < 10; ++p) { bv[p] = -3.0e38f; bx[p] = -1; }
    for (int j = 0; j < NL; ++j) {
        float v = dir ? ls[(size_t)j * NL + i] : ls[(size_t)i * NL + j];
        bool better = (v > bv[0]) || (v == bv[0] && j > bx[0]);
        if (better) {
            bv[0] = v; bx[0] = j;
#pragma unroll
            for (int p = 0; p < 9; ++p) {
                bool sw = (bv[p] > bv[p + 1]) || (bv[p] == bv[p + 1] && bx[p] > bx[p + 1]);
                if (sw) {
                    float tv = bv[p]; bv[p] = bv[p + 1]; bv[p + 1] = tv;
                    int ti = bx[p]; bx[p] = bx[p + 1]; bx[p + 1] = ti;
                }
            }
        }
    }
#pragma unroll
    for (int p = 0; p < 10; ++p)
        topk[(size_t)(dir * NL + i) * 10 + p] = bx[p];
}

// ---------------- Needleman-Wunsch on 10x10 blocks of top-10 candidates ----------
__global__ __launch_bounds__(128) void nw_kernel(
    const float* __restrict__ d1, const float* __restrict__ d2,
    const int* __restrict__ v1, const int* __restrict__ v2,
    const int* __restrict__ topk, float* __restrict__ nwout)
{
    int L = blockIdx.x;
    int dir = blockIdx.y;
    const float* Ad = dir ? d2 : d1;
    const float* Bd = dir ? d1 : d2;
    const int* vA = dir ? v2 : v1;
    const int* vB = dir ? v1 : v2;
    const int* tk = topk + (size_t)(dir * NL + L) * 10;

    __shared__ float Asl[10 * 132];
    __shared__ float Bsl[10 * 132];
    __shared__ float M[10][110];  // [cand][s*11+t]
    __shared__ int vam[10];

    int tid = threadIdx.x;
#pragma unroll
    for (int it = 0; it < 10; ++it) {
        int idx = tid + it * 128;
        int row = idx >> 7, col = idx & 127;
        Asl[row * 132 + col] = Ad[((size_t)L * 10 + row) * DD + col];
    }
    if (tid < 10) vam[tid] = vA[L * 10 + tid];

    for (int c = 0; c < 10; ++c) {
        int j = tk[c];
        __syncthreads();
#pragma unroll
        for (int it = 0; it < 10; ++it) {
            int idx = tid + it * 128;
            int row = idx >> 7, col = idx & 127;
            Bsl[row * 132 + col] = Bd[((size_t)j * 10 + row) * DD + col];
        }
        __syncthreads();
        if (tid < 100) {
            int s = tid / 10, t = tid - s * 10;
            const float4* ap = (const float4*)&Asl[s * 132];
            const float4* bp = (const float4*)&Bsl[t * 132];
            float acc = 0.0f;
#pragma unroll
            for (int k = 0; k < 32; ++k) {
                float4 a = ap[k], b = bp[k];
                acc = fmaf(a.x, b.x, acc);
                acc = fmaf(a.y, b.y, acc);
                acc = fmaf(a.z, b.z, acc);
                acc = fmaf(a.w, b.w, acc);
            }
            int ok = vam[s] && vB[j * 10 + t];
            M[c][s * 11 + t] = ok ? acc : -1.0f;
        }
    }
    __syncthreads();

    if (tid < 20) {
        int c = tid % 10, f = tid / 10;
        float prev[11];
#pragma unroll
        for (int p = 0; p < 11; ++p) prev[p] = 0.0f;
#pragma unroll
        for (int s = 0; s < 10; ++s) {
            float oldp = prev[0];
            float run = -3.0e38f;
#pragma unroll
            for (int t = 0; t < 10; ++t) {
                int tt = f ? (9 - t) : t;
                float sc = M[c][s * 11 + tt] - 0.1f;
                float pt1 = prev[t + 1];
                float av = fmaxf(pt1, oldp + sc);
                run = fmaxf(run, av);
                prev[t + 1] = fmaxf(run, 0.0f);
                oldp = pt1;
            }
        }
        nwout[((size_t)(dir * NL + L)) * 20 + f * 10 + c] = prev[10];
    }
}

// ---------------- argmax + mutual check ----------------
__global__ __launch_bounds__(512) void final_kernel(
    const float* __restrict__ nw, const int* __restrict__ topk, int* __restrict__ out)
{
    __shared__ int m1[NL], m2[NL];
    int t = threadIdx.x;
    {
        const float* p = nw + (size_t)t * 20;
        float bb = -3.0e38f; int kk = 0;
        for (int k = 0; k < 20; ++k) {
            float v = p[k];
            if (v > bb) { bb = v; kk = k; }
        }
        m1[t] = topk[(size_t)t * 10 + (kk % 10)];
    }
    {
        const float* p = nw + (size_t)(NL + t) * 20;
        float bb = -3.0e38f; int kk = 0;
        for (int k = 0; k < 20; ++k) {
            float v = p[k];
            if (v > bb) { bb = v; kk = k; }
        }
        m2[t] = topk[(size_t)(NL + t) * 10 + (kk % 10)];
    }
    __syncthreads();
    int mt = m1[t];
    out[t] = (m2[mt] == t) ? mt : -1;
}

extern "C" void kernel_launch(void* const* d_in, const int* in_sizes, int n_in,
                              void* d_out, int out_size, void* d_ws, size_t ws_size,
                              hipStream_t stream)
{
    const float* seg1 = (const float*)d_in[0];
    const float* seg2 = (const float*)d_in[1];
    const float* desc1 = (const float*)d_in[2];
    const float* desc2 = (const float*)d_in[3];
    int* out = (int*)d_out;

    char* ws = (char*)d_ws;
    size_t off = 0;
    float* dt1 = (float*)(ws + off); off += (size_t)DD * HWC * 4;        // 8 MB
    float* dt2 = (float*)(ws + off); off += (size_t)DD * HWC * 4;        // 8 MB
    float* dd1 = (float*)(ws + off); off += (size_t)NL * SS * DD * 4;    // 2.5 MB
    float* dd2 = (float*)(ws + off); off += (size_t)NL * SS * DD * 4;    // 2.5 MB
    int* v1 = (int*)(ws + off); off += (size_t)NL * SS * 4;
    int* v2 = (int*)(ws + off); off += (size_t)NL * SS * 4;
    float* ls = (float*)(ws + off); off += (size_t)NL * NL * 4;          // 1 MB
    int* topk = (int*)(ws + off); off += (size_t)2 * NL * 10 * 4;
    float* nwv = (float*)(ws + off); off += (size_t)2 * NL * 20 * 4;

    transpose_kernel<<<dim3(HWC / 32, DD / 32, 2), dim3(32, 8), 0, stream>>>(
        desc1, desc2, dt1, dt2);
    sample_kernel<<<dim3(NL, 2), 128, 0, stream>>>(
        seg1, seg2, dt1, dt2, dd1, dd2, v1, v2);
    gemm_ls_kernel<<<dim3(32, 32), 256, 0, stream>>>(dd1, dd2, v1, v2, ls);
    topk_kernel<<<2, 512, 0, stream>>>(ls, topk);
    nw_kernel<<<dim3(NL, 2), 128, 0, stream>>>(dd1, dd2, v1, v2, topk, nwv);
    final_kernel<<<1, 512, 0, stream>>>(nwv, topk, out);
}

// Round 2
// 215.677 us; speedup vs baseline: 3.5045x; 3.5045x over previous
//
#include <hip/hip_runtime.h>
#include <cmath>

#define NL 512
#define SS 10
#define DD 128
#define HWC (128 * 128)
#define LDK 36

// ---------------- transpose (D, HW) -> (HW, D), both images ----------------
__global__ __launch_bounds__(256) void transpose_kernel(
    const float* __restrict__ in1, const float* __restrict__ in2,
    float* __restrict__ out1, float* __restrict__ out2)
{
    const float* in = blockIdx.z ? in2 : in1;
    float* out = blockIdx.z ? out2 : out1;
    __shared__ float tile[32][33];
    int hw0 = blockIdx.x * 32;
    int d0 = blockIdx.y * 32;
    int tx = threadIdx.x, ty = threadIdx.y;  // 32 x 8
#pragma unroll
    for (int j = 0; j < 32; j += 8)
        tile[ty + j][tx] = in[(size_t)(d0 + ty + j) * HWC + hw0 + tx];
    __syncthreads();
#pragma unroll
    for (int j = 0; j < 32; j += 8)
        out[(size_t)(hw0 + ty + j) * DD + d0 + tx] = tile[tx][ty + j];
}

// ---------------- sample points + bilinear + normalize ----------------
__device__ __forceinline__ float fetchd(const float* __restrict__ dt, int y, int x, int d)
{
    bool inb = (x >= 0) && (x < 128) && (y >= 0) && (y < 128);
    int yc = y < 0 ? 0 : (y > 127 ? 127 : y);
    int xc = x < 0 ? 0 : (x > 127 ? 127 : x);
    float v = dt[((size_t)(yc * 128 + xc)) * DD + d];
    return inb ? v : 0.0f;
}

__global__ __launch_bounds__(128) void sample_kernel(
    const float* __restrict__ seg1, const float* __restrict__ seg2,
    const float* __restrict__ dt1, const float* __restrict__ dt2,
    float* __restrict__ dd1, float* __restrict__ dd2,
    int* __restrict__ v1, int* __restrict__ v2)
{
#pragma clang fp contract(off)
    int L = blockIdx.x;
    int img = blockIdx.y;
    const float* seg = img ? seg2 : seg1;
    const float* dt = img ? dt2 : dt1;
    float* dd = img ? dd2 : dd1;
    int* vv = img ? v2 : v1;

    float p0y = seg[L * 4 + 0], p0x = seg[L * 4 + 1];
    float p1y = seg[L * 4 + 2], p1x = seg[L * 4 + 3];
    float dy = p0y - p1y, dx = p0x - p1x;
    float len = sqrtf(dy * dy + dx * dx);
    float nf = floorf(len / 8.0f);
    nf = fminf(fmaxf(nf, 2.0f), 10.0f);
    int ni = (int)nf;
    float ivy = (p1y - p0y) / (nf - 1.0f);
    float ivx = (p1x - p0x) / (nf - 1.0f);

    int d = threadIdx.x;
    __shared__ float red[128];

    for (int t = 0; t < SS; ++t) {
        int pt = L * SS + t;
        bool val = t < ni;  // block-uniform
        float outv = 0.0f;
        if (val) {
            float py = p0y + (float)t * ivy;
            float px = p0x + (float)t * ivx;
            float gx = 2.0f * px / 511.0f - 1.0f;
            float gy = 2.0f * py / 511.0f - 1.0f;
            float ix = ((gx + 1.0f) * 128.0f - 1.0f) / 2.0f;
            float iy = ((gy + 1.0f) * 128.0f - 1.0f) / 2.0f;
            float x0f = floorf(ix), y0f = floorf(iy);
            float wx = ix - x0f, wy = iy - y0f;
            int x0 = (int)x0f, y0 = (int)y0f;
            float g00 = fetchd(dt, y0, x0, d);
            float g01 = fetchd(dt, y0, x0 + 1, d);
            float g10 = fetchd(dt, y0 + 1, x0, d);
            float g11 = fetchd(dt, y0 + 1, x0 + 1, d);
            float omwx = 1.0f - wx, omwy = 1.0f - wy;
            float v = g00 * omwy * omwx + g01 * omwy * wx + g10 * wy * omwx + g11 * wy * wx;
            red[d] = v * v;
            __syncthreads();
            for (int s = 64; s > 0; s >>= 1) {
                if (d < s) red[d] += red[d + s];
                __syncthreads();
            }
            float nrm = sqrtf(red[0]);
            outv = v / fmaxf(nrm, 1e-12f);
        }
        dd[(size_t)pt * DD + d] = outv;
        if (d == 0) vv[pt] = val ? 1 : 0;
        __syncthreads();
    }
}

// ---------------- GEMM (16x16 lines per block) + fused line-score ----------------
__global__ __launch_bounds__(256, 2) void gemm_ls_kernel(
    const float* __restrict__ d1, const float* __restrict__ d2,
    const int* __restrict__ v1, const int* __restrict__ v2,
    float* __restrict__ ls)
{
    __shared__ float As[160 * LDK];
    __shared__ float Bs[160 * LDK];
    int tid = threadIdx.x;
    int tx = tid & 15, ty = tid >> 4;
    int bi = blockIdx.y, bj = blockIdx.x;

    float acc[10][10];
#pragma unroll
    for (int i = 0; i < 10; ++i)
#pragma unroll
        for (int j = 0; j < 10; ++j) acc[i][j] = 0.0f;

    for (int kt = 0; kt < 4; ++kt) {
        __syncthreads();
#pragma unroll
        for (int it = 0; it < 5; ++it) {
            int f = tid + it * 256;       // 0..1279
            int row = f >> 3;             // 0..159
            int c4 = (f & 7) << 2;        // 0..28
            float4 a = *(const float4*)&d1[((size_t)(bi * 160 + row)) * DD + kt * 32 + c4];
            *(float4*)&As[row * LDK + c4] = a;
            int pl = row / 10, pts = row - pl * 10;
            int prow = pts * 16 + pl;     // t-major layout for B
            float4 b = *(const float4*)&d2[((size_t)(bj * 160 + row)) * DD + kt * 32 + c4];
            *(float4*)&Bs[prow * LDK + c4] = b;
        }
        __syncthreads();
#pragma unroll
        for (int k4 = 0; k4 < 8; ++k4) {
            float4 av[10];
#pragma unroll
            for (int i = 0; i < 10; ++i)
                av[i] = *(const float4*)&As[(ty * 10 + i) * LDK + k4 * 4];
#pragma unroll
            for (int j = 0; j < 10; ++j) {
                float4 b = *(const float4*)&Bs[(j * 16 + tx) * LDK + k4 * 4];
#pragma unroll
                for (int i = 0; i < 10; ++i) {
                    acc[i][j] = fmaf(av[i].x, b.x, acc[i][j]);
                    acc[i][j] = fmaf(av[i].y, b.y, acc[i][j]);
                    acc[i][j] = fmaf(av[i].z, b.z, acc[i][j]);
                    acc[i][j] = fmaf(av[i].w, b.w, acc[i][j]);
                }
            }
        }
    }

    // per-thread pair reduction: this thread owns the full 10x10 block of (iL, jL)
    int iL = bi * 16 + ty;
    int jL = bj * 16 + tx;
    int va[10], vb[10];
#pragma unroll
    for (int s = 0; s < 10; ++s) va[s] = v1[iL * 10 + s];
#pragma unroll
    for (int t = 0; t < 10; ++t) vb[t] = v2[jL * 10 + t];

    float sum1 = 0.0f; int c1 = 0;
#pragma unroll
    for (int s = 0; s < 10; ++s) {
        float mx = -3.0e38f;
#pragma unroll
        for (int t = 0; t < 10; ++t) {
            float v = (va[s] && vb[t]) ? acc[s][t] : -1.0f;
            mx = fmaxf(mx, v);
        }
        if (mx != -1.0f) { sum1 += mx; c1++; }
    }
    float sum2 = 0.0f; int c2 = 0;
#pragma unroll
    for (int t = 0; t < 10; ++t) {
        float mx = -3.0e38f;
#pragma unroll
        for (int s = 0; s < 10; ++s) {
            float v = (va[s] && vb[t]) ? acc[s][t] : -1.0f;
            mx = fmaxf(mx, v);
        }
        if (mx != -1.0f) { sum2 += mx; c2++; }
    }
    ls[(size_t)iL * NL + jL] = (sum1 / (float)c1 + sum2 / (float)c2) * 0.5f;
}

// ---------------- top-10: one wave per (line, dir), repeated max-extraction ------
// Matches stable-argsort tail semantics: output sorted ascending by (value, index);
// ties in the selected set resolve toward larger index.
__global__ __launch_bounds__(64) void topk_kernel(
    const float* __restrict__ ls, int* __restrict__ topk)
{
    int i = blockIdx.x;
    int dir = blockIdx.y;
    int lane = threadIdx.x;

    float v[8];
#pragma unroll
    for (int it = 0; it < 8; ++it) {
        int j = it * 64 + lane;
        v[it] = dir ? ls[(size_t)j * NL + i] : ls[(size_t)i * NL + j];
    }
    int* outp = &topk[(size_t)(dir * NL + i) * 10];

    for (int p = 9; p >= 0; --p) {
        float bv = -3.0e38f;
        int bi = -1;
#pragma unroll
        for (int it = 0; it < 8; ++it) {
            int j = it * 64 + lane;
            bool better = (v[it] > bv) || (v[it] == bv && j > bi);
            if (better) { bv = v[it]; bi = j; }
        }
#pragma unroll
        for (int m = 1; m < 64; m <<= 1) {
            float ov = __shfl_xor(bv, m);
            int oi = __shfl_xor(bi, m);
            bool better = (ov > bv) || (ov == bv && oi > bi);
            if (better) { bv = ov; bi = oi; }
        }
        if ((bi & 63) == lane) v[bi >> 6] = -3.0e38f;
        if (lane == 0) outp[p] = bi;
    }
}

// ---------------- Needleman-Wunsch on 10x10 blocks of top-10 candidates ----------
__global__ __launch_bounds__(128) void nw_kernel(
    const float* __restrict__ d1, const float* __restrict__ d2,
    const int* __restrict__ v1, const int* __restrict__ v2,
    const int* __restrict__ topk, float* __restrict__ nwout)
{
    int L = blockIdx.x;
    int dir = blockIdx.y;
    const float* Ad = dir ? d2 : d1;
    const float* Bd = dir ? d1 : d2;
    const int* vA = dir ? v2 : v1;
    const int* vB = dir ? v1 : v2;
    const int* tk = topk + (size_t)(dir * NL + L) * 10;

    __shared__ float Asl[10 * 132];
    __shared__ float Bsl[10 * 132];
    __shared__ float M[10][110];  // [cand][s*11+t]
    __shared__ int vam[10];

    int tid = threadIdx.x;
#pragma unroll
    for (int it = 0; it < 10; ++it) {
        int idx = tid + it * 128;
        int row = idx >> 7, col = idx & 127;
        Asl[row * 132 + col] = Ad[((size_t)L * 10 + row) * DD + col];
    }
    if (tid < 10) vam[tid] = vA[L * 10 + tid];

    for (int c = 0; c < 10; ++c) {
        int j = tk[c];
        __syncthreads();
#pragma unroll
        for (int it = 0; it < 10; ++it) {
            int idx = tid + it * 128;
            int row = idx >> 7, col = idx & 127;
            Bsl[row * 132 + col] = Bd[((size_t)j * 10 + row) * DD + col];
        }
        __syncthreads();
        if (tid < 100) {
            int s = tid / 10, t = tid - s * 10;
            const float4* ap = (const float4*)&Asl[s * 132];
            const float4* bp = (const float4*)&Bsl[t * 132];
            float acc = 0.0f;
#pragma unroll
            for (int k = 0; k < 32; ++k) {
                float4 a = ap[k], b = bp[k];
                acc = fmaf(a.x, b.x, acc);
                acc = fmaf(a.y, b.y, acc);
                acc = fmaf(a.z, b.z, acc);
                acc = fmaf(a.w, b.w, acc);
            }
            int ok = vam[s] && vB[j * 10 + t];
            M[c][s * 11 + t] = ok ? acc : -1.0f;
        }
    }
    __syncthreads();

    if (tid < 20) {
        int c = tid % 10, f = tid / 10;
        float prev[11];
#pragma unroll
        for (int p = 0; p < 11; ++p) prev[p] = 0.0f;
#pragma unroll
        for (int s = 0; s < 10; ++s) {
            float oldp = prev[0];
            float run = -3.0e38f;
#pragma unroll
            for (int t = 0; t < 10; ++t) {
                int tt = f ? (9 - t) : t;
                float sc = M[c][s * 11 + tt] - 0.1f;
                float pt1 = prev[t + 1];
                float av = fmaxf(pt1, oldp + sc);
                run = fmaxf(run, av);
                prev[t + 1] = fmaxf(run, 0.0f);
                oldp = pt1;
            }
        }
        nwout[((size_t)(dir * NL + L)) * 20 + f * 10 + c] = prev[10];
    }
}

// ---------------- argmax + mutual check ----------------
__global__ __launch_bounds__(512) void final_kernel(
    const float* __restrict__ nw, const int* __restrict__ topk, int* __restrict__ out)
{
    __shared__ int m1[NL], m2[NL];
    int t = threadIdx.x;
    {
        const float* p = nw + (size_t)t * 20;
        float bb = -3.0e38f; int kk = 0;
        for (int k = 0; k < 20; ++k) {
            float v = p[k];
            if (v > bb) { bb = v; kk = k; }
        }
        m1[t] = topk[(size_t)t * 10 + (kk % 10)];
    }
    {
        const float* p = nw + (size_t)(NL + t) * 20;
        float bb = -3.0e38f; int kk = 0;
        for (int k = 0; k < 20; ++k) {
            float v = p[k];
            if (v > bb) { bb = v; kk = k; }
        }
        m2[t] = topk[(size_t)(NL + t) * 10 + (kk % 10)];
    }
    __syncthreads();
    int mt = m1[t];
    out[t] = (m2[mt] == t) ? mt : -1;
}

extern "C" void kernel_launch(void* const* d_in, const int* in_sizes, int n_in,
                              void* d_out, int out_size, void* d_ws, size_t ws_size,
                              hipStream_t stream)
{
    const float* seg1 = (const float*)d_in[0];
    const float* seg2 = (const float*)d_in[1];
    const float* desc1 = (const float*)d_in[2];
    const float* desc2 = (const float*)d_in[3];
    int* out = (int*)d_out;

    char* ws = (char*)d_ws;
    size_t off = 0;
    float* dt1 = (float*)(ws + off); off += (size_t)DD * HWC * 4;        // 8 MB
    float* dt2 = (float*)(ws + off); off += (size_t)DD * HWC * 4;        // 8 MB
    float* dd1 = (float*)(ws + off); off += (size_t)NL * SS * DD * 4;    // 2.5 MB
    float* dd2 = (float*)(ws + off); off += (size_t)NL * SS * DD * 4;    // 2.5 MB
    int* v1 = (int*)(ws + off); off += (size_t)NL * SS * 4;
    int* v2 = (int*)(ws + off); off += (size_t)NL * SS * 4;
    float* ls = (float*)(ws + off); off += (size_t)NL * NL * 4;          // 1 MB
    int* topk = (int*)(ws + off); off += (size_t)2 * NL * 10 * 4;
    float* nwv = (float*)(ws + off); off += (size_t)2 * NL * 20 * 4;

    transpose_kernel<<<dim3(HWC / 32, DD / 32, 2), dim3(32, 8), 0, stream>>>(
        desc1, desc2, dt1, dt2);
    sample_kernel<<<dim3(NL, 2), 128, 0, stream>>>(
        seg1, seg2, dt1, dt2, dd1, dd2, v1, v2);
    gemm_ls_kernel<<<dim3(32, 32), 256, 0, stream>>>(dd1, dd2, v1, v2, ls);
    topk_kernel<<<dim3(NL, 2), 64, 0, stream>>>(ls, topk);
    nw_kernel<<<dim3(NL, 2), 128, 0, stream>>>(dd1, dd2, v1, v2, topk, nwv);
    final_kernel<<<1, 512, 0, stream>>>(nwv, topk, out);
}